// Round 2
// baseline (119346.936 us; speedup 1.0000x reference)
//
#include <hip/hip_runtime.h>
#include <cstdint>
#include <cstddef>

// ---------------- constants ----------------
#define NB    64      // batch
#define TIN   512
#define TOUT  500
#define NMEL  80
#define ENC   512
#define ATTD  128
#define ARNN  1024
#define DRNN  1024
#define PREN  256
#define NFILT 32
#define KSZ   31
#define CPAD  15

#define MEL_OFF  0
#define GATE_OFF 2560000
#define ALGN_OFF 2592000

// ws float-layout sizes
#define X_SZ      8192000   // prenet output [500][64][256]
#define PM_SZ     4194304   // processed memory [64][512][128]
#define GATES_SZ  1048576   // 4 k-split partials [4][64][4096]
#define XATT_SZ   98304     // [64][1536] = [ctx(512)|ah(1024)]
#define XDEC_SZ   163840    // [64][2560] = [ah(1024)|ctx(512)|dh(1024)]
#define AC_SZ     65536
#define DC_SZ     65536
#define AW_SZ     32768
#define AWC_SZ    32768
#define PQ_SZ     8192
#define EN_SZ     32768
#define MASK_N    8208384   // 501*64*256
#define MASK_HALF 4104192

__device__ __forceinline__ float sigf(float x) { return 1.f / (1.f + expf(-x)); }
__device__ __forceinline__ uint32_t rotl32(uint32_t v, int r) { return (v << r) | (v >> (32 - r)); }

// JAX threefry2x32 (exact: 5 groups of 4 rounds + key injections)
__device__ void tf_block(uint32_t k1, uint32_t k2, uint32_t& x0, uint32_t& x1) {
    uint32_t ks0 = k1, ks1 = k2, ks2 = k1 ^ k2 ^ 0x1BD11BDAu;
    x0 += ks0; x1 += ks1;
#define TFR(r) { x0 += x1; x1 = rotl32(x1, r); x1 ^= x0; }
    TFR(13) TFR(15) TFR(26) TFR(6)   x0 += ks1; x1 += ks2 + 1u;
    TFR(17) TFR(29) TFR(16) TFR(24)  x0 += ks2; x1 += ks0 + 2u;
    TFR(13) TFR(15) TFR(26) TFR(6)   x0 += ks0; x1 += ks1 + 3u;
    TFR(17) TFR(29) TFR(16) TFR(24)  x0 += ks1; x1 += ks2 + 4u;
    TFR(13) TFR(15) TFR(26) TFR(6)   x0 += ks2; x1 += ks0 + 5u;
#undef TFR
}

// Dropout keep masks, JAX >= 0.4.30 semantics (jax_threefry_partitionable=True):
//  - split(key) is "foldlike": dk_j = (y0, y1) of threefry_block(key, x0=0, x1=j)
//  - random_bits(key, 32, shape): element i -> block(key, x0=hi(i)=0, x1=lo(i)=i),
//    32-bit result = bits1 ^ bits2 (the two output words XOR'd)
//  - bernoulli keep iff uniform<0.5 iff top bit of bits == 0
__global__ __launch_bounds__(256) void mask_kernel(unsigned char* m1, unsigned char* m2) {
    int i = blockIdx.x * 256 + threadIdx.x;
    if (i >= MASK_N) return;
    uint32_t a0 = 0u, a1 = 0u; tf_block(0u, 42u, a0, a1);   // dk1 = (a0, a1)
    uint32_t b0 = 0u, b1 = 1u; tf_block(0u, 42u, b0, b1);   // dk2 = (b0, b1)
    uint32_t x0, x1;
    x0 = 0u; x1 = (uint32_t)i; tf_block(a0, a1, x0, x1);
    m1[i] = ((x0 ^ x1) >> 31) == 0u;
    x0 = 0u; x1 = (uint32_t)i; tf_block(b0, b1, x0, x1);
    m2[i] = ((x0 ^ x1) >> 31) == 0u;
}

// prenet layer 1: x[r][n] = relu(di[r] . w1[n]) * mask * 2 ; r = t*64+b, t<500
__global__ __launch_bounds__(256) void prenet1_kernel(
    const float* __restrict__ dec_in, const float* __restrict__ w1,
    const unsigned char* __restrict__ m1, float* __restrict__ x)
{
    int r = blockIdx.x;            // 0..31999
    int t = r >> 6, b = r & 63;
    int tid = threadIdx.x;
    __shared__ float ds[NMEL];
    if (tid < NMEL) ds[tid] = (t == 0) ? 0.f : dec_in[(size_t)b * 40000 + tid * 500 + (t - 1)];
    __syncthreads();
    float acc = 0.f;
    const float* w = w1 + tid * NMEL;
#pragma unroll
    for (int k = 0; k < NMEL; ++k) acc += ds[k] * w[k];
    acc = fmaxf(acc, 0.f);
    int flat = r * 256 + tid;
    x[flat] = m1[flat] ? acc * 2.f : 0.f;
}

// prenet layer 2 (in-place, row staged in LDS first)
__global__ __launch_bounds__(256) void prenet2_kernel(
    const float* __restrict__ w2, const unsigned char* __restrict__ m2, float* x)
{
    int r = blockIdx.x;
    int tid = threadIdx.x;
    __shared__ float xs[PREN];
    xs[tid] = x[r * 256 + tid];
    __syncthreads();
    float acc = 0.f;
    const float* w = w2 + tid * PREN;
#pragma unroll 8
    for (int k = 0; k < PREN; ++k) acc += xs[k] * w[k];
    acc = fmaxf(acc, 0.f);
    int flat = r * 256 + tid;
    x[flat] = m2[flat] ? acc * 2.f : 0.f;
}

// processed_memory[b][t][a] = memory[b][t] . wm[a]
__global__ __launch_bounds__(128) void pm_kernel(
    const float* __restrict__ memory, const float* __restrict__ wm, float* __restrict__ pm)
{
    int b = blockIdx.x, t = blockIdx.y;
    int tid = threadIdx.x;
    __shared__ float ms[ENC];
    for (int i = tid; i < ENC; i += 128) ms[i] = memory[(size_t)b * (TIN * ENC) + (size_t)t * ENC + i];
    __syncthreads();
    float acc = 0.f;
    const float* w = wm + tid * ENC;
#pragma unroll 8
    for (int k = 0; k < ENC; ++k) acc += ms[k] * w[k];
    pm[(size_t)b * (TIN * ATTD) + t * ATTD + tid] = acc;
}

// Generic K-split gates GEMM: out[ks][m][n] = sum_{k in split} X[m,k]*W[n,k]
// X split at kx1 between X1/X2; W split at kw1 between W1/W2. M=64 fixed.
__global__ __launch_bounds__(256) void gemm_gates(
    const float* __restrict__ X1, int ldx1, int kx1,
    const float* __restrict__ X2, int ldx2,
    const float* __restrict__ W1, int ldw1, int kw1,
    const float* __restrict__ W2, int ldw2,
    float* __restrict__ outp, int N, int Kq)
{
    __shared__ __align__(16) float Xs[32][68];
    __shared__ __align__(16) float Ws[32][68];
    const int tid = threadIdx.x;
    const int n0 = blockIdx.x * 64;
    const int kbeg = blockIdx.y * Kq;
    const int tn = tid & 15, tm = tid >> 4;
    float acc[4][4];
#pragma unroll
    for (int i = 0; i < 4; ++i)
#pragma unroll
        for (int j = 0; j < 4; ++j) acc[i][j] = 0.f;

    for (int k0 = kbeg; k0 < kbeg + Kq; k0 += 32) {
#pragma unroll
        for (int i = 0; i < 8; ++i) {
            int flat = i * 256 + tid;
            int m = flat >> 5, c = flat & 31;
            int k = k0 + c;
            Xs[c][m] = (k < kx1) ? X1[m * ldx1 + k] : X2[m * ldx2 + (k - kx1)];
        }
#pragma unroll
        for (int i = 0; i < 8; ++i) {
            int flat = i * 256 + tid;
            int r = flat >> 5, c = flat & 31;
            int k = k0 + c;
            int n = n0 + r;
            Ws[c][r] = (k < kw1) ? W1[n * ldw1 + k] : W2[n * ldw2 + (k - kw1)];
        }
        __syncthreads();
#pragma unroll
        for (int kk = 0; kk < 32; ++kk) {
            float4 xv = *(const float4*)&Xs[kk][tm * 4];
            float4 wv = *(const float4*)&Ws[kk][tn * 4];
            float xr[4] = { xv.x, xv.y, xv.z, xv.w };
            float wr[4] = { wv.x, wv.y, wv.z, wv.w };
#pragma unroll
            for (int i = 0; i < 4; ++i)
#pragma unroll
                for (int j = 0; j < 4; ++j) acc[i][j] += xr[i] * wr[j];
        }
        __syncthreads();
    }
    float* o = outp + (size_t)blockIdx.y * 64 * N;
#pragma unroll
    for (int i = 0; i < 4; ++i)
#pragma unroll
        for (int j = 0; j < 4; ++j)
            o[(tm * 4 + i) * N + (n0 + tn * 4 + j)] = acc[i][j];
}

// attention-LSTM pointwise (+ pq = ah @ wq.T). gp = 4 K-split partials.
__global__ __launch_bounds__(256) void att_pointwise(
    const float* __restrict__ gp, const float* __restrict__ bih, const float* __restrict__ bhh,
    float* __restrict__ ac, float* __restrict__ xcat_att, float* __restrict__ xcat_dec,
    const float* __restrict__ wq, float* __restrict__ pq)
{
    const int b = blockIdx.x, tid = threadIdx.x;
    __shared__ float hs[ARNN];
    __shared__ float red[256];
#pragma unroll
    for (int q = 0; q < 4; ++q) {
        int j = q * 256 + tid;
        float gi = bih[j] + bhh[j];
        float gf = bih[1024 + j] + bhh[1024 + j];
        float gg = bih[2048 + j] + bhh[2048 + j];
        float go = bih[3072 + j] + bhh[3072 + j];
#pragma unroll
        for (int s = 0; s < 4; ++s) {
            const float* g = gp + (size_t)s * 262144 + b * 4096;
            gi += g[j]; gf += g[1024 + j]; gg += g[2048 + j]; go += g[3072 + j];
        }
        float c = sigf(gf) * ac[b * 1024 + j] + sigf(gi) * tanhf(gg);
        float h = sigf(go) * tanhf(c);
        ac[b * 1024 + j] = c;
        xcat_att[b * 1536 + 512 + j] = h;
        xcat_dec[b * 2560 + j] = h;
        hs[j] = h;
    }
    __syncthreads();
    const int a = tid & 127, half = tid >> 7;
    float s = 0.f;
    const float* wr = wq + a * 1024 + half * 512;
    const float* hh = hs + half * 512;
#pragma unroll 8
    for (int k = 0; k < 512; ++k) s += hh[k] * wr[k];
    red[tid] = s;
    __syncthreads();
    if (half == 0) pq[b * 128 + a] = red[a] + red[a + 128];
}

// conv(aw,awc) + loc_dense + energies ; grid (64 b, 4 t-chunks of 128)
__global__ __launch_bounds__(256) void energies_kernel(
    const float* __restrict__ aw, const float* __restrict__ awc,
    const float* __restrict__ lc, const float* __restrict__ ld,
    const float* __restrict__ vvec, const float* __restrict__ pq,
    const float* __restrict__ pm, float* __restrict__ energ)
{
    const int b = blockIdx.x, tc = blockIdx.y;
    const int t0 = tc * 128;
    const int tid = threadIdx.x;
    __shared__ float awin[160], awcin[160];
    __shared__ float lcs[NFILT * 62];          // [f][2][31]
    __shared__ float locs[128 * 33];           // conv out [t][f], padded
    __shared__ float pqs[ATTD], vs[ATTD];
    __shared__ float ldm[ATTD * NFILT];        // loc_dense [a][f]
    __shared__ float ered[256];

    for (int i = tid; i < 158; i += 256) {
        int t = t0 + i - CPAD;
        bool ok = (t >= 0 && t < TIN);
        awin[i]  = ok ? aw[b * TIN + t]  : 0.f;
        awcin[i] = ok ? awc[b * TIN + t] : 0.f;
    }
    for (int i = tid; i < NFILT * 62; i += 256) lcs[i] = lc[i];
    for (int i = tid; i < ATTD * NFILT; i += 256) ldm[i] = ld[i];
    if (tid < ATTD) { pqs[tid] = pq[b * ATTD + tid]; vs[tid] = vvec[tid]; }
    __syncthreads();

    // conv: 128 t x 32 f outputs
    for (int idx = tid; idx < 128 * 32; idx += 256) {
        int tl = idx >> 5, f = idx & 31;
        const float* w0 = lcs + f * 62;
        float s = 0.f;
#pragma unroll
        for (int k = 0; k < KSZ; ++k)
            s += awin[tl + k] * w0[k] + awcin[tl + k] * w0[31 + k];
        locs[tl * 33 + f] = s;
    }
    __syncthreads();

    // energies: thread pair (tl, half) covers 64 a each
    const int tl = tid >> 1, half = tid & 1;
    float e = 0.f;
    const float* pmrow = pm + (size_t)b * (TIN * ATTD) + (size_t)(t0 + tl) * ATTD + half * 64;
    const float* lt = locs + tl * 33;
    for (int a = 0; a < 64; ++a) {
        const float* lrow = ldm + (half * 64 + a) * 32;
        float s = pqs[half * 64 + a] + pmrow[a];
#pragma unroll
        for (int f = 0; f < NFILT; ++f) s += lt[f] * lrow[f];
        e += vs[half * 64 + a] * tanhf(s);
    }
    ered[tid] = e;
    __syncthreads();
    if (half == 0) energ[b * TIN + t0 + tl] = ered[tid] + ered[tid + 1];
}

// masked softmax + aw/awc update + alignments out + ctx
__global__ __launch_bounds__(256) void softmax_ctx_kernel(
    const float* __restrict__ energ, const int* __restrict__ mlen,
    const float* __restrict__ memory,
    float* __restrict__ aw, float* __restrict__ awc,
    float* __restrict__ out_align, int t_step,
    float* __restrict__ xcat_att, float* __restrict__ xcat_dec)
{
    const int b = blockIdx.x, tid = threadIdx.x;
    const int len = mlen[b];
    __shared__ float es[TIN];
    __shared__ float red[256];
    __shared__ float ms[8][ENC];

    float e1 = (tid < len) ? energ[b * TIN + tid] : -INFINITY;
    float e2 = (tid + 256 < len) ? energ[b * TIN + tid + 256] : -INFINITY;
    red[tid] = fmaxf(e1, e2);
    __syncthreads();
    for (int s = 128; s > 0; s >>= 1) {
        if (tid < s) red[tid] = fmaxf(red[tid], red[tid + s]);
        __syncthreads();
    }
    const float mx = red[0];
    __syncthreads();
    float p1 = expf(e1 - mx);
    float p2 = expf(e2 - mx);
    red[tid] = p1 + p2;
    __syncthreads();
    for (int s = 128; s > 0; s >>= 1) {
        if (tid < s) red[tid] += red[tid + s];
        __syncthreads();
    }
    const float inv = 1.f / red[0];
    p1 *= inv; p2 *= inv;
    es[tid] = p1; es[tid + 256] = p2;

    aw[b * TIN + tid] = p1;          aw[b * TIN + tid + 256] = p2;
    awc[b * TIN + tid] += p1;        awc[b * TIN + tid + 256] += p2;
    size_t ao = (size_t)b * (TOUT * TIN) + (size_t)t_step * TIN;
    out_align[ao + tid] = p1;        out_align[ao + tid + 256] = p2;

    // ctx[d] = sum_t aw[t] * memory[b,t,d]
    float c1 = 0.f, c2 = 0.f;
    for (int tc = 0; tc < TIN; tc += 8) {
        __syncthreads();
#pragma unroll
        for (int i = 0; i < 16; ++i) {
            int flat = i * 256 + tid;
            int tt = flat >> 9, d = flat & 511;
            ms[tt][d] = memory[(size_t)b * (TIN * ENC) + (size_t)(tc + tt) * ENC + d];
        }
        __syncthreads();
#pragma unroll
        for (int j = 0; j < 8; ++j) {
            float a_ = es[tc + j];
            c1 += a_ * ms[j][tid];
            c2 += a_ * ms[j][tid + 256];
        }
    }
    xcat_att[b * 1536 + tid] = c1;
    xcat_att[b * 1536 + 256 + tid] = c2;
    xcat_dec[b * 2560 + 1024 + tid] = c1;
    xcat_dec[b * 2560 + 1024 + 256 + tid] = c2;
}

// decoder-LSTM pointwise
__global__ __launch_bounds__(256) void dec_pointwise(
    const float* __restrict__ gp, const float* __restrict__ bih, const float* __restrict__ bhh,
    float* __restrict__ dc, float* __restrict__ xcat_dec)
{
    const int b = blockIdx.x, tid = threadIdx.x;
#pragma unroll
    for (int q = 0; q < 4; ++q) {
        int j = q * 256 + tid;
        float gi = bih[j] + bhh[j];
        float gf = bih[1024 + j] + bhh[1024 + j];
        float gg = bih[2048 + j] + bhh[2048 + j];
        float go = bih[3072 + j] + bhh[3072 + j];
#pragma unroll
        for (int s = 0; s < 4; ++s) {
            const float* g = gp + (size_t)s * 262144 + b * 4096;
            gi += g[j]; gf += g[1024 + j]; gg += g[2048 + j]; go += g[3072 + j];
        }
        float c = sigf(gf) * dc[b * 1024 + j] + sigf(gi) * tanhf(gg);
        float h = sigf(go) * tanhf(c);
        dc[b * 1024 + j] = c;
        xcat_dec[b * 2560 + 1536 + j] = h;
    }
}

// mel + gate projection from dhc = [dh | ctx]
__global__ __launch_bounds__(128) void proj_kernel(
    const float* __restrict__ xcat_dec,
    const float* __restrict__ proj_w, const float* __restrict__ proj_b,
    const float* __restrict__ gate_w, const float* __restrict__ gate_b,
    float* __restrict__ out, int t_step)
{
    const int b = blockIdx.x, tid = threadIdx.x;
    __shared__ float s[1536];
    const float* xd = xcat_dec + b * 2560;
    for (int i = tid; i < 1024; i += 128) s[i] = xd[1536 + i];      // dh
    for (int i = tid; i < 512; i += 128)  s[1024 + i] = xd[1024 + i]; // ctx
    __syncthreads();
    if (tid < NMEL) {
        float acc = proj_b[tid];
        const float* w = proj_w + tid * 1536;
#pragma unroll 8
        for (int k = 0; k < 1536; ++k) acc += s[k] * w[k];
        out[MEL_OFF + (size_t)b * (TOUT * NMEL) + (size_t)t_step * NMEL + tid] = acc;
    } else if (tid == NMEL) {
        float acc = gate_b[0];
#pragma unroll 8
        for (int k = 0; k < 1536; ++k) acc += s[k] * gate_w[k];
        out[GATE_OFF + (size_t)b * TOUT + t_step] = acc;
    }
}

extern "C" void kernel_launch(void* const* d_in, const int* in_sizes, int n_in,
                              void* d_out, int out_size, void* d_ws, size_t ws_size,
                              hipStream_t stream) {
    const float* memory   = (const float*)d_in[0];
    const float* dec_in   = (const float*)d_in[1];
    const int*   mlen     = (const int*)d_in[2];
    const float* pw1      = (const float*)d_in[3];
    const float* pw2      = (const float*)d_in[4];
    const float* att_wih  = (const float*)d_in[5];
    const float* att_whh  = (const float*)d_in[6];
    const float* att_bih  = (const float*)d_in[7];
    const float* att_bhh  = (const float*)d_in[8];
    const float* wq       = (const float*)d_in[9];
    const float* wm       = (const float*)d_in[10];
    const float* v        = (const float*)d_in[11];
    const float* loc_conv = (const float*)d_in[12];
    const float* loc_dense= (const float*)d_in[13];
    const float* dec_wih  = (const float*)d_in[14];
    const float* dec_whh  = (const float*)d_in[15];
    const float* dec_bih  = (const float*)d_in[16];
    const float* dec_bhh  = (const float*)d_in[17];
    const float* proj_w   = (const float*)d_in[18];
    const float* proj_b   = (const float*)d_in[19];
    const float* gate_w   = (const float*)d_in[20];
    const float* gate_b   = (const float*)d_in[21];
    float* out = (float*)d_out;

    // ---- ws layout ----
    float* f        = (float*)d_ws;
    float* x        = f;
    float* pm       = x + X_SZ;
    float* gates    = pm + PM_SZ;
    float* xcat_att = gates + GATES_SZ;
    float* xcat_dec = xcat_att + XATT_SZ;
    float* ac       = xcat_dec + XDEC_SZ;
    float* dc       = ac + AC_SZ;
    float* aw       = dc + DC_SZ;
    float* awc      = aw + AW_SZ;
    float* pq       = awc + AWC_SZ;
    float* energ    = pq + PQ_SZ;
    unsigned char* m1 = (unsigned char*)(energ + EN_SZ);
    unsigned char* m2 = m1 + MASK_N;
    size_t need = (size_t)(m2 + MASK_N - (unsigned char*)d_ws);
    if (ws_size < need) return;   // would corrupt; fail loudly via wrong output

    // zero recurrent state (xcat_att..awc contiguous)
    size_t state_floats = (size_t)XATT_SZ + XDEC_SZ + AC_SZ + DC_SZ + AW_SZ + AWC_SZ;
    hipMemsetAsync(xcat_att, 0, state_floats * sizeof(float), stream);

    // one-time per call: dropout masks, prenet, processed memory
    mask_kernel<<<(MASK_N + 255) / 256, 256, 0, stream>>>(m1, m2);
    prenet1_kernel<<<TOUT * NB, 256, 0, stream>>>(dec_in, pw1, m1, x);
    prenet2_kernel<<<TOUT * NB, 256, 0, stream>>>(pw2, m2, x);
    pm_kernel<<<dim3(NB, TIN), 128, 0, stream>>>(memory, wm, pm);

    dim3 gg(64, 4);
    float* out_align = out + ALGN_OFF;
    for (int t = 0; t < TOUT; ++t) {
        // attention LSTM gates: X = [x_t(256) | ctx(512) | ah(1024)], W = [wih(768) | whh(1024)]
        gemm_gates<<<gg, 256, 0, stream>>>(x + (size_t)t * (NB * PREN), PREN, PREN,
                                           xcat_att, 1536,
                                           att_wih, 768, 768, att_whh, 1024,
                                           gates, 4096, 448);
        att_pointwise<<<NB, 256, 0, stream>>>(gates, att_bih, att_bhh, ac, xcat_att, xcat_dec, wq, pq);
        energies_kernel<<<dim3(NB, 4), 256, 0, stream>>>(aw, awc, loc_conv, loc_dense, v, pq, pm, energ);
        softmax_ctx_kernel<<<NB, 256, 0, stream>>>(energ, mlen, memory, aw, awc, out_align, t,
                                                   xcat_att, xcat_dec);
        // decoder LSTM gates: X = [ah(1024) | ctx(512) | dh(1024)], W = [wih(1536) | whh(1024)]
        gemm_gates<<<gg, 256, 0, stream>>>(xcat_dec, 2560, 2560,
                                           xcat_dec, 2560,
                                           dec_wih, 1536, 1536, dec_whh, 1024,
                                           gates, 4096, 640);
        dec_pointwise<<<NB, 256, 0, stream>>>(gates, dec_bih, dec_bhh, dc, xcat_dec);
        proj_kernel<<<NB, 128, 0, stream>>>(xcat_dec, proj_w, proj_b, gate_w, gate_b, out, t);
    }
}